// Round 4
// baseline (489.424 us; speedup 1.0000x reference)
//
#include <hip/hip_runtime.h>

#define NNODES 4096
#define NCH    128
#define NE     10

// ---------------- workspace layout (float elements) ----------------
// [0..16)    counts (int)
// [16..32)   offsets (int)
// [32..48)   cursor (int)
// [48..4144) list (int, q -> b)
// 4160:      T3 tables [e][c][6561]        (8,398,080)
// then       T2 tables [e][c][729]         (933,120)
// then       T1 tables [e][c][81]          (103,680)
// then       pre  [c][D][q]                (4,718,592)
// then       xg   [c][n][q]                (4,718,592)  reused as omix[q][1152] after k_main
// total ~75.5 MB

// ---------------- bucketing (parallel: count + scan + scatter) ----------------
__global__ void k_count(const float* __restrict__ attrs, int* __restrict__ counts)
{
    int b = blockIdx.x * 256 + threadIdx.x;
    if (b >= NNODES) return;
    const float* y = attrs + (size_t)b * NE;
    int e = 0;
#pragma unroll
    for (int t = 0; t < NE; ++t) if (y[t] > 0.5f) e = t;
    atomicAdd(&counts[e], 1);
}

__global__ void k_scan(const int* __restrict__ counts, int* __restrict__ offsets)
{
    if (threadIdx.x == 0 && blockIdx.x == 0) {
        int run = 0;
        for (int e = 0; e < NE; ++e) { offsets[e] = run; run += counts[e]; }
    }
}

__global__ void k_scatter(const float* __restrict__ attrs, const int* __restrict__ offsets,
                          int* __restrict__ cursor, int* __restrict__ list)
{
    int b = blockIdx.x * 256 + threadIdx.x;
    if (b >= NNODES) return;
    const float* y = attrs + (size_t)b * NE;
    int e = 0;
#pragma unroll
    for (int t = 0; t < NE; ++t) if (y[t] > 0.5f) e = t;
    int pos = atomicAdd(&cursor[e], 1);
    list[offsets[e] + pos] = b;
}

// ---------------- gather-transpose node feats ----------------
// xg[(c*9+n)*4096 + q] = nf[(list[q]*128 + c)*9 + n]
__global__ __launch_bounds__(256) void k_gather(
    const float* __restrict__ nf, const int* __restrict__ list,
    float* __restrict__ xg)
{
    __shared__ __align__(16) float tile[64 * 145];
    __shared__ int lb[64];
    int qb = blockIdx.x, ct = blockIdx.y, t = threadIdx.x;
    int c0 = ct * 16;
    if (t < 64) lb[t] = list[qb * 64 + t];
    __syncthreads();
#pragma unroll 1
    for (int k = 0; k < 36; ++k) {
        int idx = k * 256 + t;                // 64 nodes * 144 elems
        int node = idx / 144, elem = idx - node * 144;
        tile[node * 145 + elem] = nf[((size_t)lb[node] * 128 + c0) * 9 + elem];
    }
    __syncthreads();
#pragma unroll 1
    for (int k = 0; k < 36; ++k) {
        int idx = k * 256 + t;
        int node = idx & 63, re = idx >> 6;
        xg[((size_t)(c0 * 9 + re)) * NNODES + qb * 64 + node] = tile[node * 145 + re];
    }
}

// ---------------- table precompute ----------------
__global__ __launch_bounds__(256) void k_pre3(
    const float* __restrict__ U3_0, const float* __restrict__ U3_1, const float* __restrict__ U3_2,
    const float* __restrict__ W3_0, const float* __restrict__ W3_1, const float* __restrict__ W3_2,
    float* __restrict__ T3ws)
{
    int cid = blockIdx.x, e = blockIdx.y;
    const float* U3; const float* W3; int chunk0, rows, Dbase;
    if (cid < 23)      { chunk0 = cid;      rows = 729;  U3 = U3_0; W3 = W3_0; Dbase = 0; }
    else if (cid < 92) { chunk0 = cid - 23; rows = 2187; U3 = U3_1; W3 = W3_1; Dbase = 1; }
    else               { chunk0 = cid - 92; rows = 3645; U3 = U3_2; W3 = W3_2; Dbase = 4; }
    int tid = threadIdx.x;
    int c = tid & 127, sub = tid >> 7;

    float w[30];
#pragma unroll
    for (int k = 0; k < 30; ++k) w[k] = W3[((size_t)e * 30 + k) * 128 + c];

    __shared__ float tile[32 * 129];
    int row0 = chunk0 * 32;
#pragma unroll 1
    for (int rr = sub * 16; rr < sub * 16 + 16; ++rr) {
        int row = row0 + rr;
        float val = 0.0f;
        if (row < rows) {
            const float2* u2 = (const float2*)(U3 + (size_t)row * 30);
#pragma unroll
            for (int kk = 0; kk < 15; ++kk) {
                float2 uv = u2[kk];
                val = fmaf(uv.x, w[2 * kk], val);
                val = fmaf(uv.y, w[2 * kk + 1], val);
            }
        }
        tile[rr * 129 + c] = val;
    }
    __syncthreads();
#pragma unroll 1
    for (int wv = 0; wv < 16; ++wv) {
        int idx = tid + 256 * wv;
        int cc = idx >> 5, rr = idx & 31;
        int row = row0 + rr;
        if (row < rows)
            T3ws[((size_t)e * 128 + cc) * 6561 + (size_t)(Dbase * 729 + row)] = tile[rr * 129 + cc];
    }
}

// pre2 (blocks 0..3644) + pre1 (blocks 3645..4049) fused
__global__ __launch_bounds__(256) void k_pre12(
    const float* __restrict__ U2_0, const float* __restrict__ U2_1, const float* __restrict__ U2_2,
    const float* __restrict__ W2_0, const float* __restrict__ W2_1, const float* __restrict__ W2_2,
    const float* __restrict__ U1_0, const float* __restrict__ U1_1, const float* __restrict__ U1_2,
    const float* __restrict__ W1_0, const float* __restrict__ W1_1, const float* __restrict__ W1_2,
    float* __restrict__ T2ws, float* __restrict__ T1ws)
{
    int bid = blockIdx.x;
    if (bid < 3645) {
        int idx = bid * 256 + threadIdx.x;      // 933120 exact
        int dij = idx % 729;
        int c = (idx / 729) & 127;
        int e = idx / (729 * 128);
        int D = dij / 81, ij = dij - D * 81;
        const float* U2; const float* W2; int dloc;
        if (D == 0)      { U2 = U2_0; W2 = W2_0; dloc = 0; }
        else if (D < 4)  { U2 = U2_1; W2 = W2_1; dloc = D - 1; }
        else             { U2 = U2_2; W2 = W2_2; dloc = D - 4; }
        float val = 0.0f;
#pragma unroll
        for (int k = 0; k < 12; ++k)
            val = fmaf(U2[(size_t)(dloc * 81 + ij) * 12 + k], W2[((size_t)e * 12 + k) * 128 + c], val);
        T2ws[idx] = val;
    } else {
        int idx = (bid - 3645) * 256 + threadIdx.x;   // 103680 exact
        int di = idx % 81;
        int c = (idx / 81) & 127;
        int e = idx / (81 * 128);
        int D = di / 9, i = di - D * 9;
        const float* U1; const float* W1; int dloc;
        if (D == 0)      { U1 = U1_0; W1 = W1_0; dloc = 0; }
        else if (D < 4)  { U1 = U1_1; W1 = W1_1; dloc = D - 1; }
        else             { U1 = U1_2; W1 = W1_2; dloc = D - 4; }
        float val = 0.0f;
#pragma unroll
        for (int k = 0; k < 4; ++k)
            val = fmaf(U1[(size_t)(dloc * 9 + i) * 4 + k], W1[((size_t)e * 4 + k) * 128 + c], val);
        T1ws[idx] = val;
    }
}

// ---------------- main contraction ----------------
// LDS: row per (D,i,j), 12 floats (48 B, 16B-aligned -> ds_read_b128):
// [0..9)=T3[n], [9]=T2[j], [10]=T1 (j==0 rows only). 729*12*4 = 34992 B -> 4 blocks/CU.
template <int NB>
__device__ __forceinline__ void eq_proc_chunk(
    const float* __restrict__ xq, const float* __restrict__ lds,
    float* __restrict__ preq, int cb, int cnt, int lane, int wave)
{
    float x[NB][9];
#pragma unroll
    for (int t = 0; t < NB; ++t) {
        int pos = cb + t * 64 + lane;
        bool v = pos < cnt;
        int p = v ? pos : 0;
#pragma unroll
        for (int n = 0; n < 9; ++n)
            x[t][n] = v ? xq[(size_t)n * NNODES + p] : 0.0f;
    }
#pragma unroll
    for (int dd = 0; dd < 3; ++dd) {
        int D = wave * 3 + dd;
        int rowbase = D * 81;
        float acc3[NB];
#pragma unroll
        for (int t = 0; t < NB; ++t) acc3[t] = 0.0f;
#pragma unroll 1
        for (int i = 0; i < 9; ++i) {
            int ri = rowbase + i * 9;
            float t1v = lds[ri * 12 + 10];
            float acc2[NB];
#pragma unroll
            for (int t = 0; t < NB; ++t) acc2[t] = t1v;
#pragma unroll
            for (int j = 0; j < 9; ++j) {
                const float4* rp = (const float4*)&lds[(ri + j) * 12];
                float4 ra = rp[0], rb = rp[1], rc = rp[2];
                float acc1[NB];
#pragma unroll
                for (int t = 0; t < NB; ++t) acc1[t] = rc.y;   // T2
#pragma unroll
                for (int t = 0; t < NB; ++t) {
                    acc1[t] = fmaf(ra.x, x[t][0], acc1[t]);
                    acc1[t] = fmaf(ra.y, x[t][1], acc1[t]);
                    acc1[t] = fmaf(ra.z, x[t][2], acc1[t]);
                    acc1[t] = fmaf(ra.w, x[t][3], acc1[t]);
                    acc1[t] = fmaf(rb.x, x[t][4], acc1[t]);
                    acc1[t] = fmaf(rb.y, x[t][5], acc1[t]);
                    acc1[t] = fmaf(rb.z, x[t][6], acc1[t]);
                    acc1[t] = fmaf(rb.w, x[t][7], acc1[t]);
                    acc1[t] = fmaf(rc.x, x[t][8], acc1[t]);
                    acc2[t] = fmaf(acc1[t], x[t][j], acc2[t]);
                }
            }
#pragma unroll
            for (int t = 0; t < NB; ++t) acc3[t] = fmaf(acc2[t], x[t][i], acc3[t]);
        }
#pragma unroll
        for (int t = 0; t < NB; ++t) {
            int pos = cb + t * 64 + lane;
            if (pos < cnt)
                preq[(size_t)D * NNODES + pos] = acc3[t];
        }
    }
}

// grid (128 c, 10 e), block 192 = 3 waves; wave w handles D = 3w..3w+2.
// NB<=5: x[5][9]=45 + accs 15 + addr ~ 85 VGPR, cap 170 -> no spill.
__global__ __launch_bounds__(192, 3) void k_main(
    const float* __restrict__ xg, const int* __restrict__ counts,
    const int* __restrict__ offsets,
    const float* __restrict__ T3ws, const float* __restrict__ T2ws,
    const float* __restrict__ T1ws, float* __restrict__ pre)
{
    __shared__ __align__(16) float lds[729 * 12];   // 34992 B
    int c = blockIdx.x, e = blockIdx.y;
    int tid = threadIdx.x;
    const float* g3 = T3ws + ((size_t)e * NCH + c) * 6561;
    const float* g2 = T2ws + ((size_t)e * NCH + c) * 729;
    const float* g1 = T1ws + ((size_t)e * NCH + c) * 81;
    for (int idx = tid; idx < 6561; idx += 192) {
        int row = idx / 9, n = idx - row * 9;
        lds[row * 12 + n] = g3[idx];
    }
    for (int idx = tid; idx < 729; idx += 192)
        lds[idx * 12 + 9] = g2[idx];
    if (tid < 81) lds[(tid * 9) * 12 + 10] = g1[tid];
    __syncthreads();

    int wave = tid >> 6, lane = tid & 63;
    int cnt = counts[e], qstart = offsets[e];
    const float* xq = xg + (size_t)c * 9 * NNODES + qstart;
    float* preq = pre + (size_t)c * 9 * NNODES + qstart;
    for (int cb = 0; cb < cnt; cb += 320) {
        int rem = cnt - cb;
        int nb = (rem + 63) >> 6;
        if (nb > 5) nb = 5;
        switch (nb) {
            case 1: eq_proc_chunk<1>(xq, lds, preq, cb, cnt, lane, wave); break;
            case 2: eq_proc_chunk<2>(xq, lds, preq, cb, cnt, lane, wave); break;
            case 3: eq_proc_chunk<3>(xq, lds, preq, cb, cnt, lane, wave); break;
            case 4: eq_proc_chunk<4>(xq, lds, preq, cb, cnt, lane, wave); break;
            default: eq_proc_chunk<5>(xq, lds, preq, cb, cnt, lane, wave); break;
        }
    }
}

// ---------------- channel mix (writes dense q-major omix) ----------------
__global__ __launch_bounds__(256) void k_mix(
    const float* __restrict__ pre,
    const float* __restrict__ lin0, const float* __restrict__ lin1,
    const float* __restrict__ lin2, float* __restrict__ omix)
{
    int qb = blockIdx.x, D = blockIdx.y;
    int t = threadIdx.x;
    int tq = t & 15, tf = t >> 4;
    int q0 = qb * 64 + tq * 4;
    int f0 = tf * 8;
    const float* lin; int L, dl;
    if (D == 0)      { lin = lin0; L = 0; dl = 0; }
    else if (D < 4)  { lin = lin1; L = 1; dl = D - 1; }
    else             { lin = lin2; L = 2; dl = D - 4; }

    float acc[4][8];
#pragma unroll
    for (int qi = 0; qi < 4; ++qi)
#pragma unroll
        for (int ff = 0; ff < 8; ++ff) acc[qi][ff] = 0.0f;

#pragma unroll 2
    for (int c = 0; c < 128; ++c) {
        float4 pv = *(const float4*)&pre[((size_t)c * 9 + D) * NNODES + q0];
        float4 la = *(const float4*)&lin[c * 128 + f0];
        float4 lb = *(const float4*)&lin[c * 128 + f0 + 4];
        float l[8] = {la.x, la.y, la.z, la.w, lb.x, lb.y, lb.z, lb.w};
        float p[4] = {pv.x, pv.y, pv.z, pv.w};
#pragma unroll
        for (int qi = 0; qi < 4; ++qi)
#pragma unroll
            for (int ff = 0; ff < 8; ++ff)
                acc[qi][ff] = fmaf(p[qi], l[ff], acc[qi][ff]);
    }

    const float nrm = 0.08838834764831845f;   // 1/sqrt(128)
#pragma unroll
    for (int qi = 0; qi < 4; ++qi) {
        float* oq = omix + (size_t)(q0 + qi) * 1152;
        if (L == 0) {
#pragma unroll
            for (int ff = 0; ff < 8; ++ff)
                oq[f0 + ff] = nrm * acc[qi][ff];
        } else if (L == 1) {
#pragma unroll
            for (int ff = 0; ff < 8; ++ff)
                oq[128 + (f0 + ff) * 3 + dl] = nrm * acc[qi][ff];
        } else {
#pragma unroll
            for (int ff = 0; ff < 8; ++ff)
                oq[512 + (f0 + ff) * 5 + dl] = nrm * acc[qi][ff];
        }
    }
}

// ---------------- permute q->b + add sc (fully coalesced rows) ----------------
__global__ __launch_bounds__(256) void k_out(
    const float* __restrict__ omix, const int* __restrict__ list,
    const float* __restrict__ sc, float* __restrict__ out)
{
    __shared__ int lb[64];
    int qb = blockIdx.x, t = threadIdx.x;
    if (t < 64) lb[t] = list[qb * 64 + t];
    __syncthreads();
    const float4* om4 = (const float4*)(omix + (size_t)qb * 64 * 1152);
    const float4* sc4 = (const float4*)sc;
    float4* out4 = (float4*)out;
#pragma unroll 1
    for (int idx = t; idx < 64 * 288; idx += 256) {
        int row = idx / 288, v = idx - row * 288;
        int b = lb[row];
        float4 a = om4[row * 288 + v];
        float4 s = sc4[(size_t)b * 288 + v];
        a.x += s.x; a.y += s.y; a.z += s.z; a.w += s.w;
        out4[(size_t)b * 288 + v] = a;
    }
}

// ---------------- launch ----------------
extern "C" void kernel_launch(void* const* d_in, const int* in_sizes, int n_in,
                              void* d_out, int out_size, void* d_ws, size_t ws_size,
                              hipStream_t stream)
{
    const float* nf    = (const float*)d_in[0];
    const float* sc    = (const float*)d_in[1];
    const float* attrs = (const float*)d_in[2];
    const float *U3s[3], *U2s[3], *U1s[3], *W3s[3], *W2s[3], *W1s[3], *lins[3];
    for (int L = 0; L < 3; ++L) {
        const int o = 3 + 7 * L;
        U3s[L]  = (const float*)d_in[o + 0];
        U2s[L]  = (const float*)d_in[o + 1];
        U1s[L]  = (const float*)d_in[o + 2];
        W3s[L]  = (const float*)d_in[o + 3];
        W2s[L]  = (const float*)d_in[o + 4];
        W1s[L]  = (const float*)d_in[o + 5];
        lins[L] = (const float*)d_in[o + 6];
    }

    float* wsf   = (float*)d_ws;
    int* counts  = (int*)d_ws;
    int* offsets = counts + 16;
    int* cursor  = counts + 32;
    int* list    = counts + 48;
    float* T3ws = wsf + 4160;
    float* T2ws = T3ws + 8398080;
    float* T1ws = T2ws + 933120;
    float* pre  = T1ws + 103680;
    float* xg   = pre + 4718592;
    float* omix = xg;                 // xg dead after k_main

    hipMemsetAsync(d_ws, 0, 192, stream);
    k_count  <<<16, 256, 0, stream>>>(attrs, counts);
    k_scan   <<<1, 64, 0, stream>>>(counts, offsets);
    k_scatter<<<16, 256, 0, stream>>>(attrs, offsets, cursor, list);
    k_gather <<<dim3(64, 8), 256, 0, stream>>>(nf, list, xg);
    k_pre3<<<dim3(206, 10), 256, 0, stream>>>(U3s[0], U3s[1], U3s[2], W3s[0], W3s[1], W3s[2], T3ws);
    k_pre12<<<4050, 256, 0, stream>>>(U2s[0], U2s[1], U2s[2], W2s[0], W2s[1], W2s[2],
                                      U1s[0], U1s[1], U1s[2], W1s[0], W1s[1], W1s[2], T2ws, T1ws);
    k_main<<<dim3(128, 10), 192, 0, stream>>>(xg, counts, offsets, T3ws, T2ws, T1ws, pre);
    k_mix <<<dim3(64, 9), 256, 0, stream>>>(pre, lins[0], lins[1], lins[2], omix);
    k_out <<<64, 256, 0, stream>>>(omix, list, sc, (float*)d_out);
}

// Round 5
// 405.732 us; speedup vs baseline: 1.2063x; 1.2063x over previous
//
#include <hip/hip_runtime.h>

#define NNODES 4096
#define NCH    128
#define NE     10
#define TROW   8748          // 729 rows * 12 floats per (e,c)

// ---------------- workspace layout (float elements) ----------------
// [0..16)    counts (int)
// [16..32)   cursor (int)
// [48..4144) list (int, q -> b)
// 4160:      Tpk [e][c][729][12]  (11,197,440)  slot 0-8=T3, 9=T2, 10=T1(j==0 rows)
// then       pre [c][D][q]        (4,718,592)
// then       xg  [c][n][q]        (4,718,592)
// total ~82.6 MB

// ---------------- bucketing ----------------
__global__ void k_count(const float* __restrict__ attrs, int* __restrict__ counts)
{
    int b = blockIdx.x * 256 + threadIdx.x;
    if (b >= NNODES) return;
    const float* y = attrs + (size_t)b * NE;
    int e = 0;
#pragma unroll
    for (int t = 0; t < NE; ++t) if (y[t] > 0.5f) e = t;
    atomicAdd(&counts[e], 1);
}

// offsets computed inline from counts (10-element prefix, cheap)
__global__ void k_scatter(const float* __restrict__ attrs, const int* __restrict__ counts,
                          int* __restrict__ cursor, int* __restrict__ list)
{
    int b = blockIdx.x * 256 + threadIdx.x;
    if (b >= NNODES) return;
    const float* y = attrs + (size_t)b * NE;
    int e = 0;
#pragma unroll
    for (int t = 0; t < NE; ++t) if (y[t] > 0.5f) e = t;
    int off = 0;
#pragma unroll
    for (int u = 0; u < NE; ++u) off += (u < e) ? counts[u] : 0;
    int pos = atomicAdd(&cursor[e], 1);
    list[off + pos] = b;
}

// ---------------- gather-transpose node feats ----------------
// xg[(c*9+n)*4096 + q] = nf[(list[q]*128 + c)*9 + n]
__global__ __launch_bounds__(256) void k_gather(
    const float* __restrict__ nf, const int* __restrict__ list,
    float* __restrict__ xg)
{
    __shared__ __align__(16) float tile[64 * 145];
    __shared__ int lb[64];
    int qb = blockIdx.x, ct = blockIdx.y, t = threadIdx.x;
    int c0 = ct * 16;
    if (t < 64) lb[t] = list[qb * 64 + t];
    __syncthreads();
#pragma unroll 1
    for (int k = 0; k < 36; ++k) {
        int idx = k * 256 + t;                // 64 nodes * 144 elems
        int node = idx / 144, elem = idx - node * 144;
        tile[node * 145 + elem] = nf[((size_t)lb[node] * 128 + c0) * 9 + elem];
    }
    __syncthreads();
#pragma unroll 1
    for (int k = 0; k < 36; ++k) {
        int idx = k * 256 + t;
        int node = idx & 63, re = idx >> 6;
        xg[((size_t)(c0 * 9 + re)) * NNODES + qb * 64 + node] = tile[node * 145 + re];
    }
}

// ---------------- table precompute: all of T3/T2/T1 into packed Tpk ----------------
// blocks [0, 2060): T3 part (per-(e, 32-U3-row chunk), LDS transpose, coalesced-out)
// blocks [2060, 2060+3645): T2 slot-9 fills; blocks [5705, 6110): T1 slot-10 fills
__global__ __launch_bounds__(256) void k_pre(
    const float* __restrict__ U3_0, const float* __restrict__ U3_1, const float* __restrict__ U3_2,
    const float* __restrict__ W3_0, const float* __restrict__ W3_1, const float* __restrict__ W3_2,
    const float* __restrict__ U2_0, const float* __restrict__ U2_1, const float* __restrict__ U2_2,
    const float* __restrict__ W2_0, const float* __restrict__ W2_1, const float* __restrict__ W2_2,
    const float* __restrict__ U1_0, const float* __restrict__ U1_1, const float* __restrict__ U1_2,
    const float* __restrict__ W1_0, const float* __restrict__ W1_1, const float* __restrict__ W1_2,
    float* __restrict__ Tpk)
{
    int bid = blockIdx.x;
    int tid = threadIdx.x;
    if (bid < 2060) {
        // ---- T3 ----
        int e = bid / 206, cid = bid - e * 206;
        const float* U3; const float* W3; int chunk0, rows, Dbase;
        if (cid < 23)      { chunk0 = cid;      rows = 729;  U3 = U3_0; W3 = W3_0; Dbase = 0; }
        else if (cid < 92) { chunk0 = cid - 23; rows = 2187; U3 = U3_1; W3 = W3_1; Dbase = 1; }
        else               { chunk0 = cid - 92; rows = 3645; U3 = U3_2; W3 = W3_2; Dbase = 4; }
        int c = tid & 127, sub = tid >> 7;

        float w[30];
#pragma unroll
        for (int k = 0; k < 30; ++k) w[k] = W3[((size_t)e * 30 + k) * 128 + c];

        __shared__ float tile[32 * 129];
        int row0 = chunk0 * 32;
#pragma unroll 1
        for (int rr = sub * 16; rr < sub * 16 + 16; ++rr) {
            int row = row0 + rr;
            float val = 0.0f;
            if (row < rows) {
                const float2* u2 = (const float2*)(U3 + (size_t)row * 30);
#pragma unroll
                for (int kk = 0; kk < 15; ++kk) {
                    float2 uv = u2[kk];
                    val = fmaf(uv.x, w[2 * kk], val);
                    val = fmaf(uv.y, w[2 * kk + 1], val);
                }
            }
            tile[rr * 129 + c] = val;
        }
        __syncthreads();
#pragma unroll 1
        for (int wv = 0; wv < 16; ++wv) {
            int idx = tid + 256 * wv;
            int cc = idx >> 5, rr = idx & 31;
            int rg = row0 + rr;
            if (rg < rows) {
                int rq = rg / 9, rn = rg - rq * 9;
                Tpk[((size_t)e * 128 + cc) * TROW + (size_t)(Dbase * 81 + rq) * 12 + rn]
                    = tile[rr * 129 + cc];
            }
        }
    } else if (bid < 2060 + 3645) {
        // ---- T2 -> slot 9 ----
        int idx = (bid - 2060) * 256 + tid;     // 933120 exact
        int dij = idx % 729;
        int c = (idx / 729) & 127;
        int e = idx / (729 * 128);
        int D = dij / 81, ij = dij - D * 81;
        const float* U2; const float* W2; int dloc;
        if (D == 0)      { U2 = U2_0; W2 = W2_0; dloc = 0; }
        else if (D < 4)  { U2 = U2_1; W2 = W2_1; dloc = D - 1; }
        else             { U2 = U2_2; W2 = W2_2; dloc = D - 4; }
        float val = 0.0f;
#pragma unroll
        for (int k = 0; k < 12; ++k)
            val = fmaf(U2[(size_t)(dloc * 81 + ij) * 12 + k], W2[((size_t)e * 12 + k) * 128 + c], val);
        Tpk[((size_t)e * 128 + c) * TROW + (size_t)dij * 12 + 9] = val;
    } else {
        // ---- T1 -> slot 10 (rows with j==0) ----
        int idx = (bid - 2060 - 3645) * 256 + tid;   // 103680 exact
        int di = idx % 81;
        int c = (idx / 81) & 127;
        int e = idx / (81 * 128);
        int D = di / 9, i = di - D * 9;
        const float* U1; const float* W1; int dloc;
        if (D == 0)      { U1 = U1_0; W1 = W1_0; dloc = 0; }
        else if (D < 4)  { U1 = U1_1; W1 = W1_1; dloc = D - 1; }
        else             { U1 = U1_2; W1 = W1_2; dloc = D - 4; }
        float val = 0.0f;
#pragma unroll
        for (int k = 0; k < 4; ++k)
            val = fmaf(U1[(size_t)(dloc * 9 + i) * 4 + k], W1[((size_t)e * 4 + k) * 128 + c], val);
        Tpk[((size_t)e * 128 + c) * TROW + (size_t)di * 108 + 10] = val;
    }
}

// ---------------- main contraction (tables via wave-uniform scalar loads) ----------------
template <int NB>
__device__ __forceinline__ void eq_proc_chunk(
    const float* __restrict__ xq, const float* __restrict__ tb,
    float* __restrict__ preq, int cb, int cnt, int lane, int dbase)
{
    float x[NB][9];
#pragma unroll
    for (int t = 0; t < NB; ++t) {
        int pos = cb + t * 64 + lane;
        bool v = pos < cnt;
        int p = v ? pos : 0;
#pragma unroll
        for (int n = 0; n < 9; ++n)
            x[t][n] = v ? xq[(size_t)n * NNODES + p] : 0.0f;
    }
#pragma unroll
    for (int dd = 0; dd < 3; ++dd) {
        int D = dbase + dd;
        float acc3[NB];
#pragma unroll
        for (int t = 0; t < NB; ++t) acc3[t] = 0.0f;
#pragma unroll 1
        for (int i = 0; i < 9; ++i) {
            const float* gp = tb + (size_t)(D * 81 + i * 9) * 12;   // wave-uniform -> s_load
            float t1v = gp[10];
            float acc2[NB];
#pragma unroll
            for (int t = 0; t < NB; ++t) acc2[t] = t1v;
#pragma unroll
            for (int j = 0; j < 9; ++j) {
                const float* r = gp + j * 12;
                float acc1[NB];
#pragma unroll
                for (int t = 0; t < NB; ++t) acc1[t] = r[9];   // T2
#pragma unroll
                for (int t = 0; t < NB; ++t) {
                    acc1[t] = fmaf(r[0], x[t][0], acc1[t]);
                    acc1[t] = fmaf(r[1], x[t][1], acc1[t]);
                    acc1[t] = fmaf(r[2], x[t][2], acc1[t]);
                    acc1[t] = fmaf(r[3], x[t][3], acc1[t]);
                    acc1[t] = fmaf(r[4], x[t][4], acc1[t]);
                    acc1[t] = fmaf(r[5], x[t][5], acc1[t]);
                    acc1[t] = fmaf(r[6], x[t][6], acc1[t]);
                    acc1[t] = fmaf(r[7], x[t][7], acc1[t]);
                    acc1[t] = fmaf(r[8], x[t][8], acc1[t]);
                    acc2[t] = fmaf(acc1[t], x[t][j], acc2[t]);
                }
            }
#pragma unroll
            for (int t = 0; t < NB; ++t) acc3[t] = fmaf(acc2[t], x[t][i], acc3[t]);
        }
#pragma unroll
        for (int t = 0; t < NB; ++t) {
            int pos = cb + t * 64 + lane;
            if (pos < cnt)
                preq[(size_t)D * NNODES + pos] = acc3[t];
        }
    }
}

// grid (128 c, 10 e, 3 dgroup), block 64 = 1 wave. No LDS. 3840 blocks = 15/CU exact.
__global__ __launch_bounds__(64, 4) void k_main(
    const float* __restrict__ xg, const int* __restrict__ counts,
    const float* __restrict__ Tpk, float* __restrict__ pre)
{
    int c = blockIdx.x, e = blockIdx.y, dbase = blockIdx.z * 3;
    int lane = threadIdx.x;
    int cnt = counts[e];
    int qstart = 0;
    for (int u = 0; u < NE; ++u) qstart += (u < e) ? counts[u] : 0;
    const float* tb = Tpk + ((size_t)e * NCH + c) * TROW;
    const float* xq = xg + (size_t)c * 9 * NNODES + qstart;
    float* preq = pre + (size_t)c * 9 * NNODES + qstart;
    for (int cb = 0; cb < cnt; cb += 448) {
        int rem = cnt - cb;
        int nb = (rem + 63) >> 6;
        if (nb > 7) nb = 7;
        switch (nb) {
            case 1: eq_proc_chunk<1>(xq, tb, preq, cb, cnt, lane, dbase); break;
            case 2: eq_proc_chunk<2>(xq, tb, preq, cb, cnt, lane, dbase); break;
            case 3: eq_proc_chunk<3>(xq, tb, preq, cb, cnt, lane, dbase); break;
            case 4: eq_proc_chunk<4>(xq, tb, preq, cb, cnt, lane, dbase); break;
            case 5: eq_proc_chunk<5>(xq, tb, preq, cb, cnt, lane, dbase); break;
            case 6: eq_proc_chunk<6>(xq, tb, preq, cb, cnt, lane, dbase); break;
            default: eq_proc_chunk<7>(xq, tb, preq, cb, cnt, lane, dbase); break;
        }
    }
}

// ---------------- channel mix + permute + sc add (fused epilogue) ----------------
// grid (64 qb, 9 D), block 256 = (16 tq x 16 tf); thread: 4 q x 8 f.
__global__ __launch_bounds__(256) void k_mixout(
    const float* __restrict__ pre, const int* __restrict__ list,
    const float* __restrict__ sc,
    const float* __restrict__ lin0, const float* __restrict__ lin1,
    const float* __restrict__ lin2, float* __restrict__ out)
{
    int qb = blockIdx.x, D = blockIdx.y;
    int t = threadIdx.x;
    int tq = t & 15, tf = t >> 4;
    int q0 = qb * 64 + tq * 4;
    int f0 = tf * 8;
    const float* lin; int L, dl;
    if (D == 0)      { lin = lin0; L = 0; dl = 0; }
    else if (D < 4)  { lin = lin1; L = 1; dl = D - 1; }
    else             { lin = lin2; L = 2; dl = D - 4; }

    float acc[4][8];
#pragma unroll
    for (int qi = 0; qi < 4; ++qi)
#pragma unroll
        for (int ff = 0; ff < 8; ++ff) acc[qi][ff] = 0.0f;

#pragma unroll 2
    for (int c = 0; c < 128; ++c) {
        float4 pv = *(const float4*)&pre[((size_t)c * 9 + D) * NNODES + q0];
        float4 la = *(const float4*)&lin[c * 128 + f0];
        float4 lb = *(const float4*)&lin[c * 128 + f0 + 4];
        float l[8] = {la.x, la.y, la.z, la.w, lb.x, lb.y, lb.z, lb.w};
        float p[4] = {pv.x, pv.y, pv.z, pv.w};
#pragma unroll
        for (int qi = 0; qi < 4; ++qi)
#pragma unroll
            for (int ff = 0; ff < 8; ++ff)
                acc[qi][ff] = fmaf(p[qi], l[ff], acc[qi][ff]);
    }

    const float nrm = 0.08838834764831845f;   // 1/sqrt(128)
#pragma unroll
    for (int qi = 0; qi < 4; ++qi) {
        int b = list[q0 + qi];
        float* ob = out + (size_t)b * 1152;
        const float* scb = sc + (size_t)b * 1152;
        if (L == 0) {
#pragma unroll
            for (int ff = 0; ff < 8; ++ff)
                ob[f0 + ff] = fmaf(nrm, acc[qi][ff], scb[f0 + ff]);
        } else if (L == 1) {
#pragma unroll
            for (int ff = 0; ff < 8; ++ff) {
                int col = 128 + (f0 + ff) * 3 + dl;
                ob[col] = fmaf(nrm, acc[qi][ff], scb[col]);
            }
        } else {
#pragma unroll
            for (int ff = 0; ff < 8; ++ff) {
                int col = 512 + (f0 + ff) * 5 + dl;
                ob[col] = fmaf(nrm, acc[qi][ff], scb[col]);
            }
        }
    }
}

// ---------------- launch ----------------
extern "C" void kernel_launch(void* const* d_in, const int* in_sizes, int n_in,
                              void* d_out, int out_size, void* d_ws, size_t ws_size,
                              hipStream_t stream)
{
    const float* nf    = (const float*)d_in[0];
    const float* sc    = (const float*)d_in[1];
    const float* attrs = (const float*)d_in[2];
    const float *U3s[3], *U2s[3], *U1s[3], *W3s[3], *W2s[3], *W1s[3], *lins[3];
    for (int L = 0; L < 3; ++L) {
        const int o = 3 + 7 * L;
        U3s[L]  = (const float*)d_in[o + 0];
        U2s[L]  = (const float*)d_in[o + 1];
        U1s[L]  = (const float*)d_in[o + 2];
        W3s[L]  = (const float*)d_in[o + 3];
        W2s[L]  = (const float*)d_in[o + 4];
        W1s[L]  = (const float*)d_in[o + 5];
        lins[L] = (const float*)d_in[o + 6];
    }

    float* wsf   = (float*)d_ws;
    int* counts  = (int*)d_ws;
    int* cursor  = counts + 16;
    int* list    = counts + 48;
    float* Tpk = wsf + 4160;
    float* pre = Tpk + 11197440;
    float* xg  = pre + 4718592;

    hipMemsetAsync(d_ws, 0, 128, stream);   // counts + cursor
    k_count  <<<16, 256, 0, stream>>>(attrs, counts);
    k_scatter<<<16, 256, 0, stream>>>(attrs, counts, cursor, list);
    k_gather <<<dim3(64, 8), 256, 0, stream>>>(nf, list, xg);
    k_pre<<<6110, 256, 0, stream>>>(U3s[0], U3s[1], U3s[2], W3s[0], W3s[1], W3s[2],
                                    U2s[0], U2s[1], U2s[2], W2s[0], W2s[1], W2s[2],
                                    U1s[0], U1s[1], U1s[2], W1s[0], W1s[1], W1s[2], Tpk);
    k_main<<<dim3(128, 10, 3), 64, 0, stream>>>(xg, counts, Tpk, pre);
    k_mixout<<<dim3(64, 9), 256, 0, stream>>>(pre, list, sc, lins[0], lins[1], lins[2], (float*)d_out);
}

// Round 6
// 383.861 us; speedup vs baseline: 1.2750x; 1.0570x over previous
//
#include <hip/hip_runtime.h>

#define NNODES 4096
#define NCH    128
#define NE     10

// ---------------- workspace layout (float elements) ----------------
// [0..16)    counts (int)
// [16..32)   cursor (int)
// [48..4144) list (int, q -> b)
// 4160:      T3ws [e][c][6561]   (8,398,080)   (dij-major, n fastest)
// then       T2ws [e][c][729]    (933,120)
// then       T1ws [e][c][81]     (103,680)
// then       pre  [c][D][q]      (4,718,592)
// then       xg   [c][n][q]      (4,718,592)
// total ~75.5 MB

// ---------------- bucketing ----------------
__global__ void k_count(const float* __restrict__ attrs, int* __restrict__ counts)
{
    int b = blockIdx.x * 256 + threadIdx.x;
    if (b >= NNODES) return;
    const float* y = attrs + (size_t)b * NE;
    int e = 0;
#pragma unroll
    for (int t = 0; t < NE; ++t) if (y[t] > 0.5f) e = t;
    atomicAdd(&counts[e], 1);
}

__global__ void k_scatter(const float* __restrict__ attrs, const int* __restrict__ counts,
                          int* __restrict__ cursor, int* __restrict__ list)
{
    int b = blockIdx.x * 256 + threadIdx.x;
    if (b >= NNODES) return;
    const float* y = attrs + (size_t)b * NE;
    int e = 0;
#pragma unroll
    for (int t = 0; t < NE; ++t) if (y[t] > 0.5f) e = t;
    int off = 0;
#pragma unroll
    for (int u = 0; u < NE; ++u) off += (u < e) ? counts[u] : 0;
    int pos = atomicAdd(&cursor[e], 1);
    list[off + pos] = b;
}

// ---------------- fused gather + table precompute ----------------
// blocks [0,512): gather-transpose   (needs list)
// blocks [512,2572): T3   [2572,6217): T2   [6217,6622): T1   (independent)
__global__ __launch_bounds__(256) void k_gp(
    const float* __restrict__ nf, const int* __restrict__ list,
    const float* __restrict__ U3_0, const float* __restrict__ U3_1, const float* __restrict__ U3_2,
    const float* __restrict__ W3_0, const float* __restrict__ W3_1, const float* __restrict__ W3_2,
    const float* __restrict__ U2_0, const float* __restrict__ U2_1, const float* __restrict__ U2_2,
    const float* __restrict__ W2_0, const float* __restrict__ W2_1, const float* __restrict__ W2_2,
    const float* __restrict__ U1_0, const float* __restrict__ U1_1, const float* __restrict__ U1_2,
    const float* __restrict__ W1_0, const float* __restrict__ W1_1, const float* __restrict__ W1_2,
    float* __restrict__ xg, float* __restrict__ T3ws, float* __restrict__ T2ws,
    float* __restrict__ T1ws)
{
    __shared__ __align__(16) float smem[64 * 145];
    __shared__ int lb[64];
    int bid = blockIdx.x, t = threadIdx.x;
    if (bid < 512) {
        // ---- gather-transpose: xg[(c*9+n)*4096+q] = nf[(list[q]*128+c)*9+n] ----
        int qb = bid >> 3, ct = bid & 7;
        int c0 = ct * 16;
        if (t < 64) lb[t] = list[qb * 64 + t];
        __syncthreads();
#pragma unroll 1
        for (int k = 0; k < 36; ++k) {
            int idx = k * 256 + t;                // 64 nodes * 144 elems
            int node = idx / 144, elem = idx - node * 144;
            smem[node * 145 + elem] = nf[((size_t)lb[node] * 128 + c0) * 9 + elem];
        }
        __syncthreads();
#pragma unroll 1
        for (int k = 0; k < 36; ++k) {
            int idx = k * 256 + t;
            int node = idx & 63, re = idx >> 6;
            xg[((size_t)(c0 * 9 + re)) * NNODES + qb * 64 + node] = smem[node * 145 + re];
        }
    } else if (bid < 2572) {
        // ---- T3: per (e, 32-row chunk), LDS transpose, coalesced out ----
        int bid2 = bid - 512;
        int e = bid2 / 206, cid = bid2 - e * 206;
        const float* U3; const float* W3; int chunk0, rows, Dbase;
        if (cid < 23)      { chunk0 = cid;      rows = 729;  U3 = U3_0; W3 = W3_0; Dbase = 0; }
        else if (cid < 92) { chunk0 = cid - 23; rows = 2187; U3 = U3_1; W3 = W3_1; Dbase = 1; }
        else               { chunk0 = cid - 92; rows = 3645; U3 = U3_2; W3 = W3_2; Dbase = 4; }
        int c = t & 127, sub = t >> 7;
        float w[30];
#pragma unroll
        for (int k = 0; k < 30; ++k) w[k] = W3[((size_t)e * 30 + k) * 128 + c];
        float* tile = smem;                       // 32*129 = 4128 floats
        int row0 = chunk0 * 32;
#pragma unroll 1
        for (int rr = sub * 16; rr < sub * 16 + 16; ++rr) {
            int row = row0 + rr;
            float val = 0.0f;
            if (row < rows) {
                const float2* u2 = (const float2*)(U3 + (size_t)row * 30);
#pragma unroll
                for (int kk = 0; kk < 15; ++kk) {
                    float2 uv = u2[kk];
                    val = fmaf(uv.x, w[2 * kk], val);
                    val = fmaf(uv.y, w[2 * kk + 1], val);
                }
            }
            tile[rr * 129 + c] = val;
        }
        __syncthreads();
#pragma unroll 1
        for (int wv = 0; wv < 16; ++wv) {
            int idx = t + 256 * wv;
            int cc = idx >> 5, rr = idx & 31;
            int row = row0 + rr;
            if (row < rows)
                T3ws[((size_t)e * 128 + cc) * 6561 + (size_t)(Dbase * 729 + row)] = tile[rr * 129 + cc];
        }
    } else if (bid < 6217) {
        // ---- T2 (coalesced, dij-major per (e,c)) ----
        int idx = (bid - 2572) * 256 + t;         // 933120 exact
        int dij = idx % 729;
        int c = (idx / 729) & 127;
        int e = idx / (729 * 128);
        int D = dij / 81, ij = dij - D * 81;
        const float* U2; const float* W2; int dloc;
        if (D == 0)      { U2 = U2_0; W2 = W2_0; dloc = 0; }
        else if (D < 4)  { U2 = U2_1; W2 = W2_1; dloc = D - 1; }
        else             { U2 = U2_2; W2 = W2_2; dloc = D - 4; }
        float val = 0.0f;
#pragma unroll
        for (int k = 0; k < 12; ++k)
            val = fmaf(U2[(size_t)(dloc * 81 + ij) * 12 + k], W2[((size_t)e * 12 + k) * 128 + c], val);
        T2ws[idx] = val;
    } else {
        // ---- T1 (coalesced) ----
        int idx = (bid - 6217) * 256 + t;         // 103680 exact
        int di = idx % 81;
        int c = (idx / 81) & 127;
        int e = idx / (81 * 128);
        int D = di / 9, i = di - D * 9;
        const float* U1; const float* W1; int dloc;
        if (D == 0)      { U1 = U1_0; W1 = W1_0; dloc = 0; }
        else if (D < 4)  { U1 = U1_1; W1 = W1_1; dloc = D - 1; }
        else             { U1 = U1_2; W1 = W1_2; dloc = D - 4; }
        float val = 0.0f;
#pragma unroll
        for (int k = 0; k < 4; ++k)
            val = fmaf(U1[(size_t)(dloc * 9 + i) * 4 + k], W1[((size_t)e * 4 + k) * 128 + c], val);
        T1ws[idx] = val;
    }
}

// ---------------- main contraction ----------------
// One wave = all 9 D for a 128-node chunk of one (e,c). Tables via wave-uniform
// scalar loads (81 contiguous floats per i-block -> wide s_load). No LDS.
// grid (128 c, 10 e, 4 qchunk) = 5120 waves = 20/CU.
__global__ __launch_bounds__(64, 6) void k_main(
    const float* __restrict__ xg, const int* __restrict__ counts,
    const float* __restrict__ T3ws, const float* __restrict__ T2ws,
    const float* __restrict__ T1ws, float* __restrict__ pre)
{
    int c = blockIdx.x, e = blockIdx.y, z = blockIdx.z;
    int lane = threadIdx.x;
    int cnt = counts[e];
    int qstart = 0;
#pragma unroll
    for (int u = 0; u < NE; ++u) qstart += (u < e) ? counts[u] : 0;
    const float* t3 = T3ws + ((size_t)e * NCH + c) * 6561;
    const float* t2 = T2ws + ((size_t)e * NCH + c) * 729;
    const float* t1 = T1ws + ((size_t)e * NCH + c) * 81;
    const float* xq = xg + (size_t)c * 9 * NNODES + qstart;
    float* preq = pre + (size_t)c * 9 * NNODES + qstart;

#pragma unroll 1
    for (int cb = z * 128; cb < cnt; cb += 512) {
        float x[2][9];
#pragma unroll
        for (int t = 0; t < 2; ++t) {
            int pos = cb + t * 64 + lane;
            bool v = pos < cnt;
            int p = v ? pos : 0;
#pragma unroll
            for (int n = 0; n < 9; ++n)
                x[t][n] = v ? xq[(size_t)n * NNODES + p] : 0.0f;
        }
#pragma unroll 1
        for (int D = 0; D < 9; ++D) {
            float acc3[2] = {0.0f, 0.0f};
#pragma unroll 1
            for (int i = 0; i < 9; ++i) {
                const float* r3 = t3 + (size_t)(D * 81 + i * 9) * 9;   // 81 contiguous floats
                const float* r2 = t2 + (size_t)(D * 81 + i * 9);       // 9 contiguous
                float t1v = t1[D * 9 + i];
                float acc2[2] = {t1v, t1v};
#pragma unroll
                for (int j = 0; j < 9; ++j) {
                    const float* r = r3 + j * 9;
                    float t2v = r2[j];
                    float acc1[2] = {t2v, t2v};
#pragma unroll
                    for (int t = 0; t < 2; ++t) {
                        acc1[t] = fmaf(r[0], x[t][0], acc1[t]);
                        acc1[t] = fmaf(r[1], x[t][1], acc1[t]);
                        acc1[t] = fmaf(r[2], x[t][2], acc1[t]);
                        acc1[t] = fmaf(r[3], x[t][3], acc1[t]);
                        acc1[t] = fmaf(r[4], x[t][4], acc1[t]);
                        acc1[t] = fmaf(r[5], x[t][5], acc1[t]);
                        acc1[t] = fmaf(r[6], x[t][6], acc1[t]);
                        acc1[t] = fmaf(r[7], x[t][7], acc1[t]);
                        acc1[t] = fmaf(r[8], x[t][8], acc1[t]);
                        acc2[t] = fmaf(acc1[t], x[t][j], acc2[t]);
                    }
                }
                acc3[0] = fmaf(acc2[0], x[0][i], acc3[0]);
                acc3[1] = fmaf(acc2[1], x[1][i], acc3[1]);
            }
#pragma unroll
            for (int t = 0; t < 2; ++t) {
                int pos = cb + t * 64 + lane;
                if (pos < cnt)
                    preq[(size_t)D * NNODES + pos] = acc3[t];
            }
        }
    }
}

// ---------------- channel mix + permute + sc add (fused epilogue) ----------------
// grid (64 qb, 9 D), block 256 = (16 tq x 16 tf); thread: 4 q x 8 f.
__global__ __launch_bounds__(256) void k_mixout(
    const float* __restrict__ pre, const int* __restrict__ list,
    const float* __restrict__ sc,
    const float* __restrict__ lin0, const float* __restrict__ lin1,
    const float* __restrict__ lin2, float* __restrict__ out)
{
    int qb = blockIdx.x, D = blockIdx.y;
    int t = threadIdx.x;
    int tq = t & 15, tf = t >> 4;
    int q0 = qb * 64 + tq * 4;
    int f0 = tf * 8;
    const float* lin; int L, dl;
    if (D == 0)      { lin = lin0; L = 0; dl = 0; }
    else if (D < 4)  { lin = lin1; L = 1; dl = D - 1; }
    else             { lin = lin2; L = 2; dl = D - 4; }

    float acc[4][8];
#pragma unroll
    for (int qi = 0; qi < 4; ++qi)
#pragma unroll
        for (int ff = 0; ff < 8; ++ff) acc[qi][ff] = 0.0f;

#pragma unroll 2
    for (int c = 0; c < 128; ++c) {
        float4 pv = *(const float4*)&pre[((size_t)c * 9 + D) * NNODES + q0];
        float4 la = *(const float4*)&lin[c * 128 + f0];
        float4 lb = *(const float4*)&lin[c * 128 + f0 + 4];
        float l[8] = {la.x, la.y, la.z, la.w, lb.x, lb.y, lb.z, lb.w};
        float p[4] = {pv.x, pv.y, pv.z, pv.w};
#pragma unroll
        for (int qi = 0; qi < 4; ++qi)
#pragma unroll
            for (int ff = 0; ff < 8; ++ff)
                acc[qi][ff] = fmaf(p[qi], l[ff], acc[qi][ff]);
    }

    const float nrm = 0.08838834764831845f;   // 1/sqrt(128)
#pragma unroll
    for (int qi = 0; qi < 4; ++qi) {
        int b = list[q0 + qi];
        float* ob = out + (size_t)b * 1152;
        const float* scb = sc + (size_t)b * 1152;
        if (L == 0) {
#pragma unroll
            for (int ff = 0; ff < 8; ++ff)
                ob[f0 + ff] = fmaf(nrm, acc[qi][ff], scb[f0 + ff]);
        } else if (L == 1) {
#pragma unroll
            for (int ff = 0; ff < 8; ++ff) {
                int col = 128 + (f0 + ff) * 3 + dl;
                ob[col] = fmaf(nrm, acc[qi][ff], scb[col]);
            }
        } else {
#pragma unroll
            for (int ff = 0; ff < 8; ++ff) {
                int col = 512 + (f0 + ff) * 5 + dl;
                ob[col] = fmaf(nrm, acc[qi][ff], scb[col]);
            }
        }
    }
}

// ---------------- launch ----------------
extern "C" void kernel_launch(void* const* d_in, const int* in_sizes, int n_in,
                              void* d_out, int out_size, void* d_ws, size_t ws_size,
                              hipStream_t stream)
{
    const float* nf    = (const float*)d_in[0];
    const float* sc    = (const float*)d_in[1];
    const float* attrs = (const float*)d_in[2];
    const float *U3s[3], *U2s[3], *U1s[3], *W3s[3], *W2s[3], *W1s[3], *lins[3];
    for (int L = 0; L < 3; ++L) {
        const int o = 3 + 7 * L;
        U3s[L]  = (const float*)d_in[o + 0];
        U2s[L]  = (const float*)d_in[o + 1];
        U1s[L]  = (const float*)d_in[o + 2];
        W3s[L]  = (const float*)d_in[o + 3];
        W2s[L]  = (const float*)d_in[o + 4];
        W1s[L]  = (const float*)d_in[o + 5];
        lins[L] = (const float*)d_in[o + 6];
    }

    float* wsf   = (float*)d_ws;
    int* counts  = (int*)d_ws;
    int* cursor  = counts + 16;
    int* list    = counts + 48;
    float* T3ws = wsf + 4160;
    float* T2ws = T3ws + 8398080;
    float* T1ws = T2ws + 933120;
    float* pre  = T1ws + 103680;
    float* xg   = pre + 4718592;

    hipMemsetAsync(d_ws, 0, 128, stream);   // counts + cursor
    k_count  <<<16, 256, 0, stream>>>(attrs, counts);
    k_scatter<<<16, 256, 0, stream>>>(attrs, counts, cursor, list);
    k_gp<<<6622, 256, 0, stream>>>(nf, list,
                                   U3s[0], U3s[1], U3s[2], W3s[0], W3s[1], W3s[2],
                                   U2s[0], U2s[1], U2s[2], W2s[0], W2s[1], W2s[2],
                                   U1s[0], U1s[1], U1s[2], W1s[0], W1s[1], W1s[2],
                                   xg, T3ws, T2ws, T1ws);
    k_main<<<dim3(128, 10, 4), 64, 0, stream>>>(xg, counts, T3ws, T2ws, T1ws, pre);
    k_mixout<<<dim3(64, 9), 256, 0, stream>>>(pre, list, sc, lins[0], lins[1], lins[2], (float*)d_out);
}